// Round 1
// baseline (211.052 us; speedup 1.0000x reference)
//
#include <hip/hip_runtime.h>
#include <cstdint>
#include <cstddef>

#define EPS 1e-5f

typedef float    f4     __attribute__((ext_vector_type(4)));
typedef float    f2     __attribute__((ext_vector_type(2)));
typedef _Float16 half8  __attribute__((ext_vector_type(8)));
typedef _Float16 half4  __attribute__((ext_vector_type(4)));
typedef _Float16 half2v __attribute__((ext_vector_type(2)));

// LDS strides (elements)
#define S_XS 33
#define S_HV 136   // 128 + 8 halves: row stride 272B = 68 dwords -> 2-way (free) on b128 frag reads
#define S_H2 260   // 128*2 + 4 floats, 16B aligned rows
#define S_PT 9

// ---------------- K0: fp32 -> fp16 convert of f_fc2_w ----------------
__global__ __launch_bounds__(256) void k_conv(const float* __restrict__ in,
                                              _Float16* __restrict__ out) {
    int i = (blockIdx.x * 256 + threadIdx.x) * 4;
    f4 v = *(const f4*)(in + i);
    half4 h;
    h[0] = (_Float16)v[0]; h[1] = (_Float16)v[1];
    h[2] = (_Float16)v[2]; h[3] = (_Float16)v[3];
    *(half4*)(out + i) = h;
}

// ---------------- K1: weight-GRN -> softmax weights [8192][32] ----------------
// One 64-lane wave per row; lanes duplicated (f = lane&31) so full-wave
// shuffle reductions give exactly 2x the 32-wide sums (normalizes out).
__global__ __launch_bounds__(256) void k_weights(
    const float* __restrict__ x, const float* __restrict__ w1,
    const float* __restrict__ b1, const float* __restrict__ w2,
    const float* __restrict__ b2, const float* __restrict__ lng,
    const float* __restrict__ lnb, float* __restrict__ wts) {
    const int lane = threadIdx.x & 63;
    const int wv = threadIdx.x >> 6;
    const int f = lane & 31;
    const int row = blockIdx.x * 4 + wv;

    const float xv = x[row * 32 + f];

    // h[g] = elu(sum_f w1[g][f] * x[f] + b1[g]); this lane computes g = f
    float acc = b1[f];
    #pragma unroll
    for (int k = 0; k < 32; ++k)
        acc = fmaf(w1[f * 32 + k], __shfl(xv, k, 64), acc);
    float hval = acc > 0.f ? acc : __expf(acc) - 1.f;

    // h2[k] = sum_g w2[k][g] h[g] + b2[k]; a = h2[f], gate = h2[f+32]
    float a = b2[f], g = b2[f + 32];
    #pragma unroll
    for (int k = 0; k < 32; ++k) {
        float hk = __shfl(hval, k, 64);
        a = fmaf(w2[f * 32 + k], hk, a);
        g = fmaf(w2[(f + 32) * 32 + k], hk, g);
    }
    float v = xv + a * (1.f / (1.f + __expf(-g)));

    // LN over 32 (values duplicated across lane halves)
    float s = v;
    #pragma unroll
    for (int o = 1; o < 64; o <<= 1) s += __shfl_xor(s, o, 64);
    float mu = s * (1.f / 64.f);
    float d = v - mu;
    float sq = d * d;
    #pragma unroll
    for (int o = 1; o < 64; o <<= 1) sq += __shfl_xor(sq, o, 64);
    float y = d * rsqrtf(sq * (1.f / 64.f) + EPS) * lng[f] + lnb[f];

    // softmax over 32
    float m = y;
    #pragma unroll
    for (int o = 1; o < 64; o <<= 1) m = fmaxf(m, __shfl_xor(m, o, 64));
    float e = __expf(y - m);
    float se = e;
    #pragma unroll
    for (int o = 1; o < 64; o <<= 1) se += __shfl_xor(se, o, 64);
    if (lane < 32) wts[row * 32 + f] = e * 2.f / se;
}

// ---------------- K2: fused per-feature GRNs + weighted combine ----------------
// Block = 32-row tile x 16 features (fsplit=2). 256 threads = 4 waves.
// GEMM per f: D[32 x 256] = Hv[32 x 128] * W2[f]^T, f16 MFMA 16x16x32.
// Wave wv owns n-range [64*wv, 64*wv+64), both m-tiles, all 4 k-steps.
__global__ __launch_bounds__(256, 2) void k_main(
    const float* __restrict__ x,
    const _Float16* __restrict__ w2h,   // [32][256][128] fp16
    const float* __restrict__ fc1w,     // [32][128]
    const float* __restrict__ fc1b,     // [32][128]
    const float* __restrict__ fc2b,     // [32][256]
    const float* __restrict__ skw,      // [32][128]
    const float* __restrict__ skb,      // [32][128]
    const float* __restrict__ lng,      // [32][128]
    const float* __restrict__ lnb,      // [32][128]
    const float* __restrict__ wts,      // [8192][32]
    float* __restrict__ out)            // [8192][128], pre-zeroed
{
    __shared__ __align__(16) _Float16 hv[32 * S_HV];
    __shared__ __align__(16) float h2s[32 * S_H2];
    __shared__ float xs[32 * S_XS];
    __shared__ float wss[32 * S_XS];
    __shared__ f2 part[32 * S_PT];

    const int tid = threadIdx.x;
    const int tile = blockIdx.x >> 1;
    const int fbase = (blockIdx.x & 1) * 16;
    const int row0 = tile * 32;

    // stage x-tile and weights-tile (coalesced)
    for (int i = tid; i < 32 * 32; i += 256) {
        int r = i >> 5, c = i & 31;
        xs[r * S_XS + c] = x[(size_t)(row0 + r) * 32 + c];
        wss[r * S_XS + c] = wts[(size_t)(row0 + r) * 32 + c];
    }

    const int lane = tid & 63;
    const int wv = tid >> 6;
    const int l15 = lane & 15;
    const int q = lane >> 4;
    const int n0 = wv * 64;

    // hv-compute mapping: 2 h per thread, 8 rows
    const int h0 = (tid & 63) * 2;
    const int rb = (tid >> 6) * 8;
    // epilogue mapping: row er, h-range [eh, eh+16)
    const int er = tid & 31;
    const int eseg = tid >> 5;
    const int eh = eseg * 16;

    float out_acc[16];
    #pragma unroll
    for (int i = 0; i < 16; ++i) out_acc[i] = 0.f;

    __syncthreads();

    for (int fi = 0; fi < 16; ++fi) {
        const int f = fbase + fi;

        // ---- hv = elu(x_f * w1 + b1), fp16, A-fragment-friendly layout ----
        f2 w1v = *(const f2*)(fc1w + f * 128 + h0);
        f2 b1v = *(const f2*)(fc1b + f * 128 + h0);
        #pragma unroll
        for (int rr = 0; rr < 8; ++rr) {
            int r = rb + rr;
            float xv = xs[r * S_XS + f];
            float t0 = fmaf(xv, w1v[0], b1v[0]);
            float t1 = fmaf(xv, w1v[1], b1v[1]);
            t0 = t0 > 0.f ? t0 : __expf(t0) - 1.f;
            t1 = t1 > 0.f ? t1 : __expf(t1) - 1.f;
            half2v p; p[0] = (_Float16)t0; p[1] = (_Float16)t1;
            *(half2v*)&hv[r * S_HV + h0] = p;
        }
        __syncthreads();  // B1: hv ready; also fences prior-f part reads

        // ---- MFMA GEMM: A from LDS, B streamed from global as fragments ----
        f4 acc[2][4];
        {
            f4 z; z[0] = 0.f; z[1] = 0.f; z[2] = 0.f; z[3] = 0.f;
            #pragma unroll
            for (int m = 0; m < 2; ++m)
                #pragma unroll
                for (int n = 0; n < 4; ++n) acc[m][n] = z;
        }
        const _Float16* bp = w2h + ((size_t)f * 256 + n0 + l15) * 128 + 8 * q;
        #pragma unroll
        for (int kq = 0; kq < 4; ++kq) {
            const int k0 = kq * 32;
            // A-frag: A[m = l15][k = k0 + 8q + j]   (m118-verified layout)
            half8 a0 = *(const half8*)&hv[l15 * S_HV + k0 + 8 * q];
            half8 a1 = *(const half8*)&hv[(16 + l15) * S_HV + k0 + 8 * q];
            #pragma unroll
            for (int nt = 0; nt < 4; ++nt) {
                // B-frag: B[k = k0 + 8q + j][n = n0 + nt*16 + l15] = W2[g=n][h=k]
                half8 b = *(const half8*)(bp + nt * (16 * 128) + k0);
                acc[0][nt] = __builtin_amdgcn_mfma_f32_16x16x32_f16(a0, b, acc[0][nt], 0, 0, 0);
                acc[1][nt] = __builtin_amdgcn_mfma_f32_16x16x32_f16(a1, b, acc[1][nt], 0, 0, 0);
            }
        }
        // C/D layout: col = l15, row = 4q + reg (m89/m91-verified)
        #pragma unroll
        for (int m = 0; m < 2; ++m) {
            int rb2 = m * 16 + q * 4;
            #pragma unroll
            for (int nt = 0; nt < 4; ++nt) {
                int col = n0 + nt * 16 + l15;
                #pragma unroll
                for (int rg = 0; rg < 4; ++rg)
                    h2s[(rb2 + rg) * S_H2 + col] = acc[m][nt][rg];
            }
        }
        __syncthreads();  // B2: h2 ready

        // ---- epilogue phase A: glu + skip, per-row partial sums ----
        float xv = xs[er * S_XS + f];
        float vv[16];
        float s = 0.f, sq = 0.f;
        #pragma unroll
        for (int j = 0; j < 4; ++j) {
            f4 A  = *(const f4*)&h2s[er * S_H2 + eh + j * 4];
            f4 G  = *(const f4*)&h2s[er * S_H2 + 128 + eh + j * 4];
            f4 BA = *(const f4*)(fc2b + f * 256 + eh + j * 4);
            f4 BG = *(const f4*)(fc2b + f * 256 + 128 + eh + j * 4);
            f4 SW = *(const f4*)(skw + f * 128 + eh + j * 4);
            f4 SB = *(const f4*)(skb + f * 128 + eh + j * 4);
            #pragma unroll
            for (int c = 0; c < 4; ++c) {
                float a = A[c] + BA[c];
                float g = G[c] + BG[c];
                float sig = 1.f / (1.f + __expf(-g));
                float val = fmaf(xv, SW[c], SB[c]) + a * sig;
                vv[j * 4 + c] = val;
                s += val;
                sq = fmaf(val, val, sq);
            }
        }
        {
            f2 pp; pp[0] = s; pp[1] = sq;
            part[er * S_PT + eseg] = pp;
        }
        __syncthreads();  // B3: partials ready

        // ---- epilogue phase B: LN + weighted accumulate (registers) ----
        float ss = 0.f, qq = 0.f;
        #pragma unroll
        for (int i = 0; i < 8; ++i) {
            f2 pp = part[er * S_PT + i];
            ss += pp[0]; qq += pp[1];
        }
        float mu = ss * (1.f / 128.f);
        float var = qq * (1.f / 128.f) - mu * mu;
        float rstd = rsqrtf(fmaxf(var, 0.f) + EPS);
        float wrow = wss[er * S_XS + f];
        #pragma unroll
        for (int j = 0; j < 4; ++j) {
            f4 LG = *(const f4*)(lng + f * 128 + eh + j * 4);
            f4 LB = *(const f4*)(lnb + f * 128 + eh + j * 4);
            #pragma unroll
            for (int c = 0; c < 4; ++c) {
                float y = (vv[j * 4 + c] - mu) * rstd * LG[c] + LB[c];
                out_acc[j * 4 + c] = fmaf(wrow, y, out_acc[j * 4 + c]);
            }
        }
        // next iteration writes hv (disjoint from part/h2s read sets) then B1
    }

    // ---- combine: transpose through LDS for coalesced atomics ----
    #pragma unroll
    for (int i = 0; i < 16; ++i)
        h2s[er * S_H2 + eh + i] = out_acc[i];
    __syncthreads();
    const int oh = tid & 127;
    const int org = (tid >> 7) * 16;
    #pragma unroll
    for (int rr = 0; rr < 16; ++rr) {
        int r = org + rr;
        // exactly 2 adds per address (two f-halves); fp32 add is commutative -> deterministic
        atomicAdd(&out[(size_t)(row0 + r) * 128 + oh], h2s[r * S_H2 + oh]);
    }
}

extern "C" void kernel_launch(void* const* d_in, const int* in_sizes, int n_in,
                              void* d_out, int out_size, void* d_ws, size_t ws_size,
                              hipStream_t stream) {
    const float* x     = (const float*)d_in[0];
    const float* wg1w  = (const float*)d_in[1];
    const float* wg1b  = (const float*)d_in[2];
    const float* wg2w  = (const float*)d_in[3];
    const float* wg2b  = (const float*)d_in[4];
    const float* wglng = (const float*)d_in[5];
    const float* wglnb = (const float*)d_in[6];
    const float* fc1w  = (const float*)d_in[7];
    const float* fc1b  = (const float*)d_in[8];
    const float* fc2w  = (const float*)d_in[9];
    const float* fc2b  = (const float*)d_in[10];
    const float* skw   = (const float*)d_in[11];
    const float* skb   = (const float*)d_in[12];
    const float* lng   = (const float*)d_in[13];
    const float* lnb   = (const float*)d_in[14];
    float* out = (float*)d_out;

    _Float16* w2h = (_Float16*)d_ws;                  // 2 MB: fp16 f_fc2_w
    float* wts = (float*)((char*)d_ws + (2u << 20));  // 1 MB: softmax weights

    k_conv<<<dim3(1024), dim3(256), 0, stream>>>(fc2w, w2h);
    k_weights<<<dim3(2048), dim3(256), 0, stream>>>(x, wg1w, wg1b, wg2w, wg2b,
                                                    wglng, wglnb, wts);
    hipMemsetAsync(out, 0, (size_t)out_size * sizeof(float), stream);
    k_main<<<dim3(512), dim3(256), 0, stream>>>(x, w2h, fc1w, fc1b, fc2b,
                                                skw, skb, lng, lnb, wts, out);
}

// Round 2
// 184.572 us; speedup vs baseline: 1.1435x; 1.1435x over previous
//
#include <hip/hip_runtime.h>
#include <cstdint>
#include <cstddef>

#define EPS 1e-5f

typedef float    f4     __attribute__((ext_vector_type(4)));
typedef float    f2     __attribute__((ext_vector_type(2)));
typedef _Float16 half8  __attribute__((ext_vector_type(8)));
typedef _Float16 half4  __attribute__((ext_vector_type(4)));
typedef _Float16 half2v __attribute__((ext_vector_type(2)));

#define S_HV 136   // halves; row stride 272 B
#define S_XS 33
#define S_OUT 132
#define F_BLK 8    // features per k_main block (fsplit = 4)

// ---------------- K0: fp32 -> fp16 convert of f_fc2_w ----------------
__global__ __launch_bounds__(256) void k_conv(const float* __restrict__ in,
                                              _Float16* __restrict__ out) {
    int i = (blockIdx.x * 256 + threadIdx.x) * 4;
    f4 v = *(const f4*)(in + i);
    half4 h;
    h[0] = (_Float16)v[0]; h[1] = (_Float16)v[1];
    h[2] = (_Float16)v[2]; h[3] = (_Float16)v[3];
    *(half4*)(out + i) = h;
}

// ---------------- K1: weight-GRN -> softmax weights [8192][32] ----------------
// 32 rows/block; w1, w2, x-tile staged in padded LDS (the old version's
// per-lane scattered global row reads were ~100 us of TCP serialization).
__global__ __launch_bounds__(256) void k_weights(
    const float* __restrict__ x, const float* __restrict__ w1,
    const float* __restrict__ b1, const float* __restrict__ w2,
    const float* __restrict__ b2, const float* __restrict__ lng,
    const float* __restrict__ lnb, float* __restrict__ wts) {
    __shared__ float w1s[32 * S_XS];
    __shared__ float w2s[64 * S_XS];
    __shared__ float xsW[32 * S_XS];

    const int tid = threadIdx.x;
    const int lane = tid & 63;
    const int f = lane & 31;
    const int wv = tid >> 6;
    const int row0 = blockIdx.x * 32;

    for (int i = tid; i < 1024; i += 256) {
        int r = i >> 5, c = i & 31;
        w1s[r * S_XS + c] = w1[i];
        xsW[r * S_XS + c] = x[(size_t)row0 * 32 + i];
    }
    for (int i = tid; i < 2048; i += 256) {
        int r = i >> 5, c = i & 31;
        w2s[r * S_XS + c] = w2[i];
    }
    const float b1f = b1[f], b2a = b2[f], b2g = b2[f + 32];
    const float lgf = lng[f], lbf = lnb[f];
    __syncthreads();

    for (int rr = 0; rr < 8; ++rr) {
        const int r = wv * 8 + rr;
        // h[f] = elu(sum_k w1[f][k] x[k] + b1[f])
        float acc = b1f;
        #pragma unroll
        for (int k = 0; k < 32; ++k)
            acc = fmaf(w1s[f * S_XS + k], xsW[r * S_XS + k], acc);
        float hval = acc > 0.f ? acc : __expf(acc) - 1.f;

        float a = b2a, g = b2g;
        #pragma unroll
        for (int k = 0; k < 32; ++k) {
            float hk = __shfl(hval, k, 64);
            a = fmaf(w2s[f * S_XS + k], hk, a);
            g = fmaf(w2s[(f + 32) * S_XS + k], hk, g);
        }
        float xv = xsW[r * S_XS + f];
        float v = xv + a * (1.f / (1.f + __expf(-g)));

        // LN over 32 (lane halves duplicated -> 2x sums normalize out)
        float s = v;
        #pragma unroll
        for (int o = 1; o < 64; o <<= 1) s += __shfl_xor(s, o, 64);
        float mu = s * (1.f / 64.f);
        float d = v - mu;
        float sq = d * d;
        #pragma unroll
        for (int o = 1; o < 64; o <<= 1) sq += __shfl_xor(sq, o, 64);
        float y = d * rsqrtf(sq * (1.f / 64.f) + EPS) * lgf + lbf;

        float m = y;
        #pragma unroll
        for (int o = 1; o < 64; o <<= 1) m = fmaxf(m, __shfl_xor(m, o, 64));
        float e = __expf(y - m);
        float se = e;
        #pragma unroll
        for (int o = 1; o < 64; o <<= 1) se += __shfl_xor(se, o, 64);
        if (lane < 32) wts[(size_t)(row0 + r) * 32 + f] = e * 2.f / se;
    }
}

// ---------------- K2: fused per-feature GRNs + weighted combine ----------------
// Block = 32 rows x 8 features. Transposed MFMA: A = W2[f] (m = g-index,
// streamed from global), B = hv^T (n = batch, from LDS). Wave wv owns
// g in [32wv,32wv+32) U [128+32wv, ...): GLU pairs in-lane, LN row-sum =
// 2-level shfl_xor over q + 1 KB cross-wave partial. One barrier per f
// (hv and part double-buffered).
__global__ __launch_bounds__(256, 4) void k_main(
    const float* __restrict__ x,
    const _Float16* __restrict__ w2h,   // [32][256][128] fp16
    const float* __restrict__ fc1w,     // [32][128]
    const float* __restrict__ fc1b,     // [32][128]
    const float* __restrict__ fc2b,     // [32][256]
    const float* __restrict__ skw,      // [32][128]
    const float* __restrict__ skb,      // [32][128]
    const float* __restrict__ lng,      // [32][128]
    const float* __restrict__ lnb,      // [32][128]
    const float* __restrict__ wts,      // [8192][32]
    float* __restrict__ out)            // [8192][128], pre-zeroed
{
    __shared__ __align__(16) _Float16 hvs[2 * 32 * S_HV];   // 17408 B
    __shared__ float xs[32 * S_XS];                         // 4224 B
    __shared__ float wss[32 * S_XS];                        // 4224 B
    __shared__ f2 part[2 * 32 * 5];                         // 2560 B
    float* outs = (float*)hvs;  // overlay: 32*132*4 = 16896 B <= 17408

    const int tid = threadIdx.x;
    const int tile = blockIdx.x >> 2;
    const int fbase = (blockIdx.x & 3) * F_BLK;
    const int row0 = tile * 32;

    for (int i = tid; i < 1024; i += 256) {
        int r = i >> 5, c = i & 31;
        xs[r * S_XS + c] = x[(size_t)row0 * 32 + i];
        wss[r * S_XS + c] = wts[(size_t)row0 * 32 + i];
    }

    const int lane = tid & 63;
    const int wv = tid >> 6;
    const int l15 = lane & 15;
    const int q = lane >> 4;
    const int ga0 = wv * 32;        // this wave's a-g base
    const int h0 = lane * 2;        // hv-compute h pair
    const int rb = wv * 8;          // hv-compute row base

    float out_acc[2][2][4];
    #pragma unroll
    for (int mt = 0; mt < 2; ++mt)
        #pragma unroll
        for (int n = 0; n < 2; ++n)
            #pragma unroll
            for (int rg = 0; rg < 4; ++rg) out_acc[mt][n][rg] = 0.f;

    auto compute_hv = [&](int f, _Float16* hb) {
        f2 w1v = *(const f2*)(fc1w + f * 128 + h0);
        f2 b1v = *(const f2*)(fc1b + f * 128 + h0);
        #pragma unroll
        for (int rr = 0; rr < 8; ++rr) {
            int r = rb + rr;
            float xv = xs[r * S_XS + f];
            float t0 = fmaf(xv, w1v[0], b1v[0]);
            float t1 = fmaf(xv, w1v[1], b1v[1]);
            t0 = t0 > 0.f ? t0 : __expf(t0) - 1.f;
            t1 = t1 > 0.f ? t1 : __expf(t1) - 1.f;
            half2v pk; pk[0] = (_Float16)t0; pk[1] = (_Float16)t1;
            *(half2v*)&hb[r * S_HV + h0] = pk;
        }
    };

    __syncthreads();               // xs/wss staged
    compute_hv(fbase, hvs);
    __syncthreads();               // hv[0] ready

    int p = 0;
    for (int fi = 0; fi < F_BLK; ++fi) {
        const int f = fbase + fi;
        const _Float16* hb = hvs + p * (32 * S_HV);

        // ---- MFMA: D[g][batch] = W2[f] . hv^T ----
        f4 acc[4][2];   // [mt: a0,a1,g0,g1][n-tile]
        {
            f4 z; z[0] = 0.f; z[1] = 0.f; z[2] = 0.f; z[3] = 0.f;
            #pragma unroll
            for (int mt = 0; mt < 4; ++mt) { acc[mt][0] = z; acc[mt][1] = z; }
        }
        const _Float16* wb = w2h + ((size_t)f * 256 + l15) * 128 + 8 * q;
        #pragma unroll
        for (int kq = 0; kq < 4; ++kq) {
            const int k0 = kq * 32;
            half8 b0 = *(const half8*)&hb[l15 * S_HV + k0 + 8 * q];
            half8 b1 = *(const half8*)&hb[(16 + l15) * S_HV + k0 + 8 * q];
            #pragma unroll
            for (int mt = 0; mt < 4; ++mt) {
                const int gb = ga0 + (mt & 1) * 16 + (mt >> 1) * 128;
                half8 a = *(const half8*)(wb + (size_t)gb * 128 + k0);
                acc[mt][0] = __builtin_amdgcn_mfma_f32_16x16x32_f16(a, b0, acc[mt][0], 0, 0, 0);
                acc[mt][1] = __builtin_amdgcn_mfma_f32_16x16x32_f16(a, b1, acc[mt][1], 0, 0, 0);
            }
        }

        // ---- GLU + skip + per-batch partial sums (in-lane, C-layout) ----
        float vv[2][2][4];
        float sn[2] = {0.f, 0.f}, sqn[2] = {0.f, 0.f};
        float xvn[2];
        xvn[0] = xs[l15 * S_XS + f];
        xvn[1] = xs[(16 + l15) * S_XS + f];
        #pragma unroll
        for (int mt = 0; mt < 2; ++mt) {
            #pragma unroll
            for (int rg = 0; rg < 4; ++rg) {
                const int h = ga0 + 16 * mt + 4 * q + rg;
                float ba = fc2b[f * 256 + h];
                float bg = fc2b[f * 256 + 128 + h];
                float sw = skw[f * 128 + h];
                float sb = skb[f * 128 + h];
                #pragma unroll
                for (int n = 0; n < 2; ++n) {
                    float a = acc[mt][n][rg] + ba;
                    float g = acc[mt + 2][n][rg] + bg;
                    float sig = 1.f / (1.f + __expf(-g));
                    float val = fmaf(xvn[n], sw, sb) + a * sig;
                    vv[mt][n][rg] = val;
                    sn[n] += val;
                    sqn[n] = fmaf(val, val, sqn[n]);
                }
            }
        }
        // reduce over q (lanes xor 16, 32)
        #pragma unroll
        for (int o = 16; o < 64; o <<= 1) {
            #pragma unroll
            for (int n = 0; n < 2; ++n) {
                sn[n] += __shfl_xor(sn[n], o, 64);
                sqn[n] += __shfl_xor(sqn[n], o, 64);
            }
        }
        if (q == 0) {
            #pragma unroll
            for (int n = 0; n < 2; ++n) {
                f2 pr; pr[0] = sn[n]; pr[1] = sqn[n];
                part[p * 160 + (n * 16 + l15) * 5 + wv] = pr;
            }
        }

        if (fi + 1 < F_BLK) compute_hv(f + 1, hvs + (1 - p) * (32 * S_HV));
        __syncthreads();   // the single per-f barrier

        // ---- LN + weighted accumulate ----
        float mu_[2], wr_[2], wl_[2];
        #pragma unroll
        for (int n = 0; n < 2; ++n) {
            const int c = n * 16 + l15;
            f2 t0 = part[p * 160 + c * 5 + 0];
            f2 t1 = part[p * 160 + c * 5 + 1];
            f2 t2 = part[p * 160 + c * 5 + 2];
            f2 t3 = part[p * 160 + c * 5 + 3];
            float ss = (t0[0] + t1[0]) + (t2[0] + t3[0]);
            float qv = (t0[1] + t1[1]) + (t2[1] + t3[1]);
            float mu = ss * (1.f / 128.f);
            float var = qv * (1.f / 128.f) - mu * mu;
            float rstd = rsqrtf(fmaxf(var, 0.f) + EPS);
            float wrow = wss[c * S_XS + f];
            mu_[n] = mu; wr_[n] = wrow * rstd; wl_[n] = wrow;
        }
        #pragma unroll
        for (int mt = 0; mt < 2; ++mt) {
            #pragma unroll
            for (int rg = 0; rg < 4; ++rg) {
                const int h = ga0 + 16 * mt + 4 * q + rg;
                float lg = lng[f * 128 + h];
                float lb = lnb[f * 128 + h];
                #pragma unroll
                for (int n = 0; n < 2; ++n) {
                    float u = (vv[mt][n][rg] - mu_[n]) * wr_[n];
                    out_acc[mt][n][rg] = fmaf(u, lg, fmaf(wl_[n], lb, out_acc[mt][n][rg]));
                }
            }
        }
        p ^= 1;
    }

    // ---- final: transpose through LDS overlay, coalesced atomics ----
    // (after last barrier all waves only touch part/regs, hv region is free)
    __syncthreads();
    #pragma unroll
    for (int mt = 0; mt < 2; ++mt)
        #pragma unroll
        for (int n = 0; n < 2; ++n)
            #pragma unroll
            for (int rg = 0; rg < 4; ++rg)
                outs[(n * 16 + l15) * S_OUT + ga0 + 16 * mt + 4 * q + rg] =
                    out_acc[mt][n][rg];
    __syncthreads();
    const int oh = tid & 127;
    const int r0b = (tid >> 7) * 16;
    #pragma unroll
    for (int rr = 0; rr < 16; ++rr) {
        int r = r0b + rr;
        atomicAdd(&out[(size_t)(row0 + r) * 128 + oh], outs[r * S_OUT + oh]);
    }
}

extern "C" void kernel_launch(void* const* d_in, const int* in_sizes, int n_in,
                              void* d_out, int out_size, void* d_ws, size_t ws_size,
                              hipStream_t stream) {
    const float* x     = (const float*)d_in[0];
    const float* wg1w  = (const float*)d_in[1];
    const float* wg1b  = (const float*)d_in[2];
    const float* wg2w  = (const float*)d_in[3];
    const float* wg2b  = (const float*)d_in[4];
    const float* wglng = (const float*)d_in[5];
    const float* wglnb = (const float*)d_in[6];
    const float* fc1w  = (const float*)d_in[7];
    const float* fc1b  = (const float*)d_in[8];
    const float* fc2w  = (const float*)d_in[9];
    const float* fc2b  = (const float*)d_in[10];
    const float* skw   = (const float*)d_in[11];
    const float* skb   = (const float*)d_in[12];
    const float* lng   = (const float*)d_in[13];
    const float* lnb   = (const float*)d_in[14];
    float* out = (float*)d_out;

    _Float16* w2h = (_Float16*)d_ws;                  // 2 MB fp16 f_fc2_w
    float* wts = (float*)((char*)d_ws + (2u << 20));  // 1 MB softmax weights

    k_conv<<<dim3(1024), dim3(256), 0, stream>>>(fc2w, w2h);
    k_weights<<<dim3(256), dim3(256), 0, stream>>>(x, wg1w, wg1b, wg2w, wg2b,
                                                   wglng, wglnb, wts);
    hipMemsetAsync(out, 0, (size_t)out_size * sizeof(float), stream);
    k_main<<<dim3(1024), dim3(256), 0, stream>>>(x, w2h, fc1w, fc1b, fc2b,
                                                 skw, skb, lng, lnb, wts, out);
}